// Round 1
// baseline (75.789 us; speedup 1.0000x reference)
//
#include <hip/hip_runtime.h>
#include <cfloat>

// Problem constants (fixed by the reference): B=8, N=4096, NUM_CLASS=13, C=3.
constexpr int Bb    = 8;
constexpr int Nn    = 4096;
constexpr int NC    = 13;
constexpr int BLOCK = 512;        // 8 waves
constexpr int ICH   = Nn / 256;   // 16 i-chunks of 256 i's
constexpr int NW    = BLOCK / 64; // 8 waves per block
constexpr int JSL   = Nn / NW;    // 512 j's per wave (disjoint slice)
constexpr int JT    = JSL / 32;   // 16 j-tiles per wave
// Grid = 2 dir * 8 b * 16 chunk = 256 blocks -> exactly 1 block/CU, 2 waves/SIMD.

typedef __attribute__((ext_vector_type(8)))  short          short8;
typedef __attribute__((ext_vector_type(8)))  unsigned short ushort8;
typedef __attribute__((ext_vector_type(16))) float          floatx16;

// fp32 -> bf16 round-to-nearest-even (bit trick; inputs are finite).
static __device__ inline unsigned short f2bf(float f) {
    unsigned u = __builtin_bit_cast(unsigned, f);
    return (unsigned short)((u + 0x7FFFu + ((u >> 16) & 1u)) >> 16);
}
static __device__ inline float bf2f(unsigned short h) {
    return __builtin_bit_cast(float, (unsigned)h << 16);
}

// Work split (v2): each wave holds ALL 256 block-i's as 8 B-fragments in
// registers and sweeps a DISJOINT 512-j slice. One A-fragment (built
// in-register from 3 global floats, no LDS staging) feeds 8 independent
// MFMAs -> 8x ILP per load, no 64KB ytile, no staging barrier, and LDS
// traffic drops from 1024 ds_read_b128/CU to zero (only an 8KB partial-min
// combine remains).
// A fragment per target point j: {yh0, yh1, yh2, h1, h2, 0, 0, 0} with
// h1+h2 ~= |yhat|^2 (two-term bf16 split). B per 32-i group: lanes 0-31 =
// {-2xh0,-2xh1,-2xh2, 1, 1, 0,0,0}, lanes 32-63 = 0 (they feed k=8..15).
// One v_mfma_f32_32x32x16_bf16 per (32j x 32i) tile; v_min3 chains reduce
// the 16 C-values/lane; shfl_xor(32) merges row halves. xx_i is constant
// per i -> added back in the epilogue together with the NLL gather (dir 0).
__global__ __launch_bounds__(BLOCK)
void criterion_fused_kernel(const float* __restrict__ seg_prob,
                            const int*   __restrict__ seg_label,
                            const float* __restrict__ point_rec,
                            const float* __restrict__ point,
                            float*       __restrict__ out) {
    __shared__ float partial[NW * 256];   // 8 KB: per-wave partial mins
    __shared__ float wsum[NW];

    const int blk   = blockIdx.x;
    const int chunk = blk & (ICH - 1);
    const int b     = (blk >> 4) & (Bb - 1);
    const int dir   = blk >> 7;
    const int t     = threadIdx.x;
    const int lane  = t & 63;
    const int wave  = t >> 6;
    const int l31   = lane & 31;
    const bool lo   = (lane < 32);

    const float* __restrict__ xbase =
        (dir ? point : point_rec) + (size_t)(b * Nn + chunk * 256) * 3;
    const float* __restrict__ ybase =
        (dir ? point_rec : point) + (size_t)b * Nn * 3;

    // ---- B fragments: 8 i-groups of 32, identical across waves ----
    short8 bf[8];
    #pragma unroll
    for (int f = 0; f < 8; ++f) {
        const float* xp = xbase + (size_t)(f * 32 + l31) * 3;
        const float a0 = bf2f(f2bf(xp[0]));
        const float a1 = bf2f(f2bf(xp[1]));
        const float a2 = bf2f(f2bf(xp[2]));
        ushort8 bu;
        bu[0] = lo ? f2bf(-2.0f * a0) : (unsigned short)0;
        bu[1] = lo ? f2bf(-2.0f * a1) : (unsigned short)0;
        bu[2] = lo ? f2bf(-2.0f * a2) : (unsigned short)0;
        bu[3] = lo ? (unsigned short)0x3F80 : (unsigned short)0;   // bf16 1.0
        bu[4] = lo ? (unsigned short)0x3F80 : (unsigned short)0;
        bu[5] = 0; bu[6] = 0; bu[7] = 0;
        bf[f] = __builtin_bit_cast(short8, bu);
    }

    floatx16 zc;
    #pragma unroll
    for (int q = 0; q < 16; ++q) zc[q] = 0.0f;

    // Min accumulators: 8 frags x 4 chains, all statically indexed.
    float m[8][4];
    #pragma unroll
    for (int f = 0; f < 8; ++f)
        #pragma unroll
        for (int q = 0; q < 4; ++q) m[f][q] = FLT_MAX;

    // ---- main loop: this wave's 16 j-tiles; A built in-register ----
    // Lanes 32-63 duplicate lanes 0-31 (same address -> coalescer merges);
    // they feed k=8..15, which multiplies B's zeroed upper half.
    const float* yl = ybase + (size_t)(wave * JSL + l31) * 3;
    float c0 = yl[0], c1 = yl[1], c2 = yl[2];
    #pragma unroll 2
    for (int jt = 0; jt < JT; ++jt) {
        float n0 = 0.0f, n1 = 0.0f, n2 = 0.0f;
        if (jt + 1 < JT) {                         // rotating 1-tile prefetch
            const float* q = yl + (size_t)(jt + 1) * 96;
            n0 = q[0]; n1 = q[1]; n2 = q[2];
        }
        const unsigned short yh0 = f2bf(c0);
        const unsigned short yh1 = f2bf(c1);
        const unsigned short yh2 = f2bf(c2);
        const float yf0 = bf2f(yh0), yf1 = bf2f(yh1), yf2 = bf2f(yh2);
        const float yy  = fmaf(yf2, yf2, fmaf(yf1, yf1, yf0 * yf0));
        const unsigned short h1 = f2bf(yy);
        const unsigned short h2 = f2bf(yy - bf2f(h1));
        ushort8 av;
        av[0] = yh0; av[1] = yh1; av[2] = yh2; av[3] = h1; av[4] = h2;
        av[5] = 0;   av[6] = 0;   av[7] = 0;
        const short8 af = __builtin_bit_cast(short8, av);

        #pragma unroll
        for (int f = 0; f < 8; ++f) {
            const floatx16 d =
                __builtin_amdgcn_mfma_f32_32x32x16_bf16(af, bf[f], zc, 0, 0, 0);
            m[f][0] = fminf(fminf(d[0],  d[1]),  m[f][0]);   // v_min3 each
            m[f][1] = fminf(fminf(d[2],  d[3]),  m[f][1]);
            m[f][2] = fminf(fminf(d[4],  d[5]),  m[f][2]);
            m[f][3] = fminf(fminf(d[6],  d[7]),  m[f][3]);
            m[f][0] = fminf(fminf(d[8],  d[9]),  m[f][0]);
            m[f][1] = fminf(fminf(d[10], d[11]), m[f][1]);
            m[f][2] = fminf(fminf(d[12], d[13]), m[f][2]);
            m[f][3] = fminf(fminf(d[14], d[15]), m[f][3]);
        }
        c0 = n0; c1 = n1; c2 = n2;
    }

    // ---- per-wave partial mins -> LDS ----
    #pragma unroll
    for (int f = 0; f < 8; ++f) {
        float mm = fminf(fminf(m[f][0], m[f][1]), fminf(m[f][2], m[f][3]));
        mm = fminf(mm, __shfl_xor(mm, 32, 64));   // merge row halves
        if (lo) partial[wave * 256 + f * 32 + l31] = mm;
    }
    __syncthreads();

    // ---- epilogue: combine across waves, add xx_i and NLL, block-sum ----
    float v = 0.0f;
    if (t < 256) {
        float mm = partial[t];
        #pragma unroll
        for (int w = 1; w < NW; ++w) mm = fminf(mm, partial[w * 256 + t]);
        const float* xp = xbase + (size_t)t * 3;
        const float a0 = bf2f(f2bf(xp[0]));
        const float a1 = bf2f(f2bf(xp[1]));
        const float a2 = bf2f(f2bf(xp[2]));
        v = fmaf(a2, a2, fmaf(a1, a1, fmaf(a0, a0, mm)));
        if (dir == 0) {
            const int gi = b * Nn + chunk * 256 + t;
            v -= seg_prob[(size_t)gi * NC + (size_t)seg_label[gi]];
        }
    }
    for (int off = 32; off > 0; off >>= 1)
        v += __shfl_down(v, off, 64);
    if ((t & 63) == 0) wsum[t >> 6] = v;
    __syncthreads();
    if (t == 0) {
        float s = 0.0f;
        #pragma unroll
        for (int w = 0; w < NW; ++w) s += wsum[w];
        atomicAdd(out, s * (1.0f / (Bb * Nn)));
    }
}

extern "C" void kernel_launch(void* const* d_in, const int* in_sizes, int n_in,
                              void* d_out, int out_size, void* d_ws, size_t ws_size,
                              hipStream_t stream) {
    const float* seg_prob  = (const float*)d_in[0];
    const int*   seg_label = (const int*)d_in[1];
    const float* point_rec = (const float*)d_in[2];
    const float* point     = (const float*)d_in[3];
    float*       out       = (float*)d_out;

    hipMemsetAsync(out, 0, sizeof(float), stream);
    criterion_fused_kernel<<<dim3(2 * Bb * ICH), dim3(BLOCK), 0, stream>>>(
        seg_prob, seg_label, point_rec, point, out);
}

// Round 2
// 74.988 us; speedup vs baseline: 1.0107x; 1.0107x over previous
//
#include <hip/hip_runtime.h>
#include <cfloat>

// Problem constants (fixed by the reference): B=8, N=4096, NUM_CLASS=13, C=3.
constexpr int Bb    = 8;
constexpr int Nn    = 4096;
constexpr int NC    = 13;
constexpr int BLOCK = 512;        // 8 waves
constexpr int ICH   = Nn / 256;   // 16 i-chunks of 256 i's
constexpr int NW    = BLOCK / 64; // 8 waves per block
constexpr int JSL   = Nn / NW;    // 512 j's per wave (disjoint slice)
constexpr int JT    = JSL / 32;   // 16 j-tiles per wave
constexpr int GRID  = 2 * Bb * ICH;  // 256 blocks -> 1 block/CU

typedef __attribute__((ext_vector_type(8)))  short          short8;
typedef __attribute__((ext_vector_type(8)))  unsigned short ushort8;
typedef __attribute__((ext_vector_type(16))) float          floatx16;

// fp32 -> bf16 round-to-nearest-even (bit trick; inputs are finite).
static __device__ inline unsigned short f2bf(float f) {
    unsigned u = __builtin_bit_cast(unsigned, f);
    return (unsigned short)((u + 0x7FFFu + ((u >> 16) & 1u)) >> 16);
}
static __device__ inline float bf2f(unsigned short h) {
    return __builtin_bit_cast(float, (unsigned)h << 16);
}

// v3: identical compute to v2; the ONLY change is the final reduction.
// v0-v2 ended with 256 blocks atomicAdd-ing the same 4-byte address; all
// blocks finish compute within ~1us of each other (1 block/CU), so those
// 256 same-line device-scope RMWs serialize at the coherence point
// (~300 cyc each ~ 25us tail, common to both prior structures -- explains
// why the v2 restructure was neutral). Now each block does ONE plain store
// of its partial to d_ws[blk]; a 1-block epilogue kernel sums the 256
// partials and writes out with '=', which also removes the hipMemsetAsync
// dispatch (dispatch count unchanged: 2).
__global__ __launch_bounds__(BLOCK)
void criterion_fused_kernel(const float* __restrict__ seg_prob,
                            const int*   __restrict__ seg_label,
                            const float* __restrict__ point_rec,
                            const float* __restrict__ point,
                            float*       __restrict__ partials) {
    __shared__ float partial[NW * 256];   // 8 KB: per-wave partial mins
    __shared__ float wsum[NW];

    const int blk   = blockIdx.x;
    const int chunk = blk & (ICH - 1);
    const int b     = (blk >> 4) & (Bb - 1);
    const int dir   = blk >> 7;
    const int t     = threadIdx.x;
    const int lane  = t & 63;
    const int wave  = t >> 6;
    const int l31   = lane & 31;
    const bool lo   = (lane < 32);

    const float* __restrict__ xbase =
        (dir ? point : point_rec) + (size_t)(b * Nn + chunk * 256) * 3;
    const float* __restrict__ ybase =
        (dir ? point_rec : point) + (size_t)b * Nn * 3;

    // ---- B fragments: 8 i-groups of 32, identical across waves ----
    short8 bf[8];
    #pragma unroll
    for (int f = 0; f < 8; ++f) {
        const float* xp = xbase + (size_t)(f * 32 + l31) * 3;
        const float a0 = bf2f(f2bf(xp[0]));
        const float a1 = bf2f(f2bf(xp[1]));
        const float a2 = bf2f(f2bf(xp[2]));
        ushort8 bu;
        bu[0] = lo ? f2bf(-2.0f * a0) : (unsigned short)0;
        bu[1] = lo ? f2bf(-2.0f * a1) : (unsigned short)0;
        bu[2] = lo ? f2bf(-2.0f * a2) : (unsigned short)0;
        bu[3] = lo ? (unsigned short)0x3F80 : (unsigned short)0;   // bf16 1.0
        bu[4] = lo ? (unsigned short)0x3F80 : (unsigned short)0;
        bu[5] = 0; bu[6] = 0; bu[7] = 0;
        bf[f] = __builtin_bit_cast(short8, bu);
    }

    floatx16 zc;
    #pragma unroll
    for (int q = 0; q < 16; ++q) zc[q] = 0.0f;

    // Min accumulators: 8 frags x 4 chains, all statically indexed.
    float m[8][4];
    #pragma unroll
    for (int f = 0; f < 8; ++f)
        #pragma unroll
        for (int q = 0; q < 4; ++q) m[f][q] = FLT_MAX;

    // ---- main loop: this wave's 16 j-tiles; A built in-register ----
    // Lanes 32-63 duplicate lanes 0-31 (same address -> coalescer merges);
    // they feed k=8..15, which multiplies B's zeroed upper half.
    const float* yl = ybase + (size_t)(wave * JSL + l31) * 3;
    float c0 = yl[0], c1 = yl[1], c2 = yl[2];
    #pragma unroll 2
    for (int jt = 0; jt < JT; ++jt) {
        float n0 = 0.0f, n1 = 0.0f, n2 = 0.0f;
        if (jt + 1 < JT) {                         // rotating 1-tile prefetch
            const float* q = yl + (size_t)(jt + 1) * 96;
            n0 = q[0]; n1 = q[1]; n2 = q[2];
        }
        const unsigned short yh0 = f2bf(c0);
        const unsigned short yh1 = f2bf(c1);
        const unsigned short yh2 = f2bf(c2);
        const float yf0 = bf2f(yh0), yf1 = bf2f(yh1), yf2 = bf2f(yh2);
        const float yy  = fmaf(yf2, yf2, fmaf(yf1, yf1, yf0 * yf0));
        const unsigned short h1 = f2bf(yy);
        const unsigned short h2 = f2bf(yy - bf2f(h1));
        ushort8 av;
        av[0] = yh0; av[1] = yh1; av[2] = yh2; av[3] = h1; av[4] = h2;
        av[5] = 0;   av[6] = 0;   av[7] = 0;
        const short8 af = __builtin_bit_cast(short8, av);

        #pragma unroll
        for (int f = 0; f < 8; ++f) {
            const floatx16 d =
                __builtin_amdgcn_mfma_f32_32x32x16_bf16(af, bf[f], zc, 0, 0, 0);
            m[f][0] = fminf(fminf(d[0],  d[1]),  m[f][0]);   // v_min3 each
            m[f][1] = fminf(fminf(d[2],  d[3]),  m[f][1]);
            m[f][2] = fminf(fminf(d[4],  d[5]),  m[f][2]);
            m[f][3] = fminf(fminf(d[6],  d[7]),  m[f][3]);
            m[f][0] = fminf(fminf(d[8],  d[9]),  m[f][0]);
            m[f][1] = fminf(fminf(d[10], d[11]), m[f][1]);
            m[f][2] = fminf(fminf(d[12], d[13]), m[f][2]);
            m[f][3] = fminf(fminf(d[14], d[15]), m[f][3]);
        }
        c0 = n0; c1 = n1; c2 = n2;
    }

    // ---- per-wave partial mins -> LDS ----
    #pragma unroll
    for (int f = 0; f < 8; ++f) {
        float mm = fminf(fminf(m[f][0], m[f][1]), fminf(m[f][2], m[f][3]));
        mm = fminf(mm, __shfl_xor(mm, 32, 64));   // merge row halves
        if (lo) partial[wave * 256 + f * 32 + l31] = mm;
    }
    __syncthreads();

    // ---- epilogue: combine across waves, add xx_i and NLL, block-sum ----
    float v = 0.0f;
    if (t < 256) {
        float mm = partial[t];
        #pragma unroll
        for (int w = 1; w < NW; ++w) mm = fminf(mm, partial[w * 256 + t]);
        const float* xp = xbase + (size_t)t * 3;
        const float a0 = bf2f(f2bf(xp[0]));
        const float a1 = bf2f(f2bf(xp[1]));
        const float a2 = bf2f(f2bf(xp[2]));
        v = fmaf(a2, a2, fmaf(a1, a1, fmaf(a0, a0, mm)));
        if (dir == 0) {
            const int gi = b * Nn + chunk * 256 + t;
            v -= seg_prob[(size_t)gi * NC + (size_t)seg_label[gi]];
        }
    }
    for (int off = 32; off > 0; off >>= 1)
        v += __shfl_down(v, off, 64);
    if ((t & 63) == 0) wsum[t >> 6] = v;
    __syncthreads();
    if (t == 0) {
        float s = 0.0f;
        #pragma unroll
        for (int w = 0; w < NW; ++w) s += wsum[w];
        partials[blk] = s;                 // ONE plain store per block
    }
}

// 1-block epilogue: sum the 256 per-block partials, scale, write out.
__global__ __launch_bounds__(256)
void final_reduce_kernel(const float* __restrict__ partials,
                         float*       __restrict__ out) {
    __shared__ float ws[4];
    const int t = threadIdx.x;
    float v = partials[t];
    for (int off = 32; off > 0; off >>= 1)
        v += __shfl_down(v, off, 64);
    if ((t & 63) == 0) ws[t >> 6] = v;
    __syncthreads();
    if (t == 0)
        *out = (ws[0] + ws[1] + ws[2] + ws[3]) * (1.0f / (Bb * Nn));
}

extern "C" void kernel_launch(void* const* d_in, const int* in_sizes, int n_in,
                              void* d_out, int out_size, void* d_ws, size_t ws_size,
                              hipStream_t stream) {
    const float* seg_prob  = (const float*)d_in[0];
    const int*   seg_label = (const int*)d_in[1];
    const float* point_rec = (const float*)d_in[2];
    const float* point     = (const float*)d_in[3];
    float*       out       = (float*)d_out;
    float*       partials  = (float*)d_ws;   // 256 floats, rewritten each launch

    criterion_fused_kernel<<<dim3(GRID), dim3(BLOCK), 0, stream>>>(
        seg_prob, seg_label, point_rec, point, partials);
    final_reduce_kernel<<<dim3(1), dim3(256), 0, stream>>>(partials, out);
}

// Round 3
// 71.418 us; speedup vs baseline: 1.0612x; 1.0500x over previous
//
#include <hip/hip_runtime.h>
#include <cfloat>

// Problem constants (fixed by the reference): B=8, N=4096, NUM_CLASS=13, C=3.
constexpr int Bb    = 8;
constexpr int Nn    = 4096;
constexpr int NC    = 13;
constexpr int BLOCK = 512;        // 8 waves
constexpr int ICH   = Nn / 256;   // 16 i-chunks of 256 i's
constexpr int NW    = BLOCK / 64; // 8 waves per block
constexpr int JSL   = Nn / NW;    // 512 j's per wave (disjoint LDS slice)
constexpr int JT    = JSL / 32;   // 16 j-tiles per wave
constexpr int GRID  = 2 * Bb * ICH;  // 256 blocks -> 1 block/CU

typedef __attribute__((ext_vector_type(8)))  short          short8;
typedef __attribute__((ext_vector_type(8)))  unsigned short ushort8;
typedef __attribute__((ext_vector_type(16))) float          floatx16;

// fp32 -> bf16 round-to-nearest-even (bit trick; inputs are finite).
static __device__ inline unsigned short f2bf(float f) {
    unsigned u = __builtin_bit_cast(unsigned, f);
    return (unsigned short)((u + 0x7FFFu + ((u >> 16) & 1u)) >> 16);
}
static __device__ inline float bf2f(unsigned short h) {
    return __builtin_bit_cast(float, (unsigned)h << 16);
}

// v4 = best of v0 + v2 + v3:
//  - v0's cooperative global->LDS Y staging: 24 independent dword loads per
//    thread issued in one burst -> the post-poison cold-memory latency
//    (~900cy; the 268MB harness fill evicts L2+L3 every iteration) is paid
//    ONCE in parallel, not 16x sequentially per wave (v2's depth-1 prefetch
//    chain -- the measured +4us regression).
//  - v2's work split for the main loop: each wave holds all 256 block-i's
//    as 8 B-fragments in registers and sweeps a DISJOINT 512-j LDS slice.
//    One ds_read_b128 feeds 8 independent MFMAs -> 128 ds_reads/block
//    (8x fewer than v0) and MFMA latency fully hidden.
//  - v3's atomic-free finish (one plain store per block + 1-block reduce);
//    proven neutral vs atomics but keeps the tail clean.
// Math identical to v0-v3: t(j,i) = yy - 2x.y via one v_mfma_f32_32x32x16_bf16
// per 32x32 tile (A={y0,y1,y2,h1,h2,0,0,0}, B lanes0-31={-2x0,-2x1,-2x2,1,1,...},
// lanes32-63=0); xx_i re-added in the epilogue with the NLL gather (dir 0).
__global__ __launch_bounds__(BLOCK)
void criterion_fused_kernel(const float* __restrict__ seg_prob,
                            const int*   __restrict__ seg_label,
                            const float* __restrict__ point_rec,
                            const float* __restrict__ point,
                            float*       __restrict__ partials) {
    __shared__ ushort8 ytile[Nn];          // 64 KB
    __shared__ float   partial[NW * 256];  // 8 KB: per-wave partial mins
    __shared__ float   wsum[NW];

    const int blk   = blockIdx.x;
    const int chunk = blk & (ICH - 1);
    const int b     = (blk >> 4) & (Bb - 1);
    const int dir   = blk >> 7;
    const int t     = threadIdx.x;
    const int lane  = t & 63;
    const int wave  = t >> 6;
    const int l31   = lane & 31;
    const bool lo   = (lane < 32);

    const float* __restrict__ xbase =
        (dir ? point : point_rec) + (size_t)(b * Nn + chunk * 256) * 3;
    const float* __restrict__ ybase =
        (dir ? point_rec : point) + (size_t)b * Nn * 3;

    // ---- stage the full Y row: 8 points/thread, strided layout ----
    // (lane-consecutive 16B ds_write_b128 -> conflict-free; loads per q are
    //  512 threads x 12B contiguous -> coalesced; all 24 dwords independent)
    #pragma unroll
    for (int q = 0; q < Nn / BLOCK; ++q) {
        const int p = q * BLOCK + t;
        const float* yp = ybase + (size_t)p * 3;
        const unsigned short yh0 = f2bf(yp[0]);
        const unsigned short yh1 = f2bf(yp[1]);
        const unsigned short yh2 = f2bf(yp[2]);
        const float yf0 = bf2f(yh0), yf1 = bf2f(yh1), yf2 = bf2f(yh2);
        const float yy  = fmaf(yf2, yf2, fmaf(yf1, yf1, yf0 * yf0));
        const unsigned short h1 = f2bf(yy);
        const unsigned short h2 = f2bf(yy - bf2f(h1));
        ushort8 v;
        v[0] = yh0; v[1] = yh1; v[2] = yh2; v[3] = h1; v[4] = h2;
        v[5] = 0;   v[6] = 0;   v[7] = 0;
        ytile[p] = v;
    }

    // ---- B fragments: 8 i-groups of 32, identical across waves ----
    short8 bf[8];
    #pragma unroll
    for (int f = 0; f < 8; ++f) {
        const float* xp = xbase + (size_t)(f * 32 + l31) * 3;
        const float a0 = bf2f(f2bf(xp[0]));
        const float a1 = bf2f(f2bf(xp[1]));
        const float a2 = bf2f(f2bf(xp[2]));
        ushort8 bu;
        bu[0] = lo ? f2bf(-2.0f * a0) : (unsigned short)0;
        bu[1] = lo ? f2bf(-2.0f * a1) : (unsigned short)0;
        bu[2] = lo ? f2bf(-2.0f * a2) : (unsigned short)0;
        bu[3] = lo ? (unsigned short)0x3F80 : (unsigned short)0;   // bf16 1.0
        bu[4] = lo ? (unsigned short)0x3F80 : (unsigned short)0;
        bu[5] = 0; bu[6] = 0; bu[7] = 0;
        bf[f] = __builtin_bit_cast(short8, bu);
    }

    floatx16 zc;
    #pragma unroll
    for (int q = 0; q < 16; ++q) zc[q] = 0.0f;

    // Min accumulators: 8 frags x 4 chains, all statically indexed.
    float m[8][4];
    #pragma unroll
    for (int f = 0; f < 8; ++f)
        #pragma unroll
        for (int q = 0; q < 4; ++q) m[f][q] = FLT_MAX;

    __syncthreads();

    // ---- main loop: this wave's 16 j-tiles from LDS; 8 MFMAs per ds_read ----
    // Lanes 32-63 duplicate lanes 0-31 (2-way LDS broadcast, free); they feed
    // k=8..15, which multiplies B's zeroed upper half.
    const int jb = wave * JSL;
    #pragma unroll 2
    for (int jt = 0; jt < JT; ++jt) {
        const short8 af = __builtin_bit_cast(short8, ytile[jb + jt * 32 + l31]);
        #pragma unroll
        for (int f = 0; f < 8; ++f) {
            const floatx16 d =
                __builtin_amdgcn_mfma_f32_32x32x16_bf16(af, bf[f], zc, 0, 0, 0);
            m[f][0] = fminf(fminf(d[0],  d[1]),  m[f][0]);   // v_min3 each
            m[f][1] = fminf(fminf(d[2],  d[3]),  m[f][1]);
            m[f][2] = fminf(fminf(d[4],  d[5]),  m[f][2]);
            m[f][3] = fminf(fminf(d[6],  d[7]),  m[f][3]);
            m[f][0] = fminf(fminf(d[8],  d[9]),  m[f][0]);
            m[f][1] = fminf(fminf(d[10], d[11]), m[f][1]);
            m[f][2] = fminf(fminf(d[12], d[13]), m[f][2]);
            m[f][3] = fminf(fminf(d[14], d[15]), m[f][3]);
        }
    }

    // ---- per-wave partial mins -> LDS ----
    #pragma unroll
    for (int f = 0; f < 8; ++f) {
        float mm = fminf(fminf(m[f][0], m[f][1]), fminf(m[f][2], m[f][3]));
        mm = fminf(mm, __shfl_xor(mm, 32, 64));   // merge row halves
        if (lo) partial[wave * 256 + f * 32 + l31] = mm;
    }
    __syncthreads();

    // ---- epilogue: combine across waves, add xx_i and NLL, block-sum ----
    float v = 0.0f;
    if (t < 256) {
        float mm = partial[t];
        #pragma unroll
        for (int w = 1; w < NW; ++w) mm = fminf(mm, partial[w * 256 + t]);
        const float* xp = xbase + (size_t)t * 3;
        const float a0 = bf2f(f2bf(xp[0]));
        const float a1 = bf2f(f2bf(xp[1]));
        const float a2 = bf2f(f2bf(xp[2]));
        v = fmaf(a2, a2, fmaf(a1, a1, fmaf(a0, a0, mm)));
        if (dir == 0) {
            const int gi = b * Nn + chunk * 256 + t;
            v -= seg_prob[(size_t)gi * NC + (size_t)seg_label[gi]];
        }
    }
    for (int off = 32; off > 0; off >>= 1)
        v += __shfl_down(v, off, 64);
    if ((t & 63) == 0) wsum[t >> 6] = v;
    __syncthreads();
    if (t == 0) {
        float s = 0.0f;
        #pragma unroll
        for (int w = 0; w < NW; ++w) s += wsum[w];
        partials[blk] = s;                 // ONE plain store per block
    }
}

// 1-block epilogue: sum the 256 per-block partials, scale, write out.
__global__ __launch_bounds__(256)
void final_reduce_kernel(const float* __restrict__ partials,
                         float*       __restrict__ out) {
    __shared__ float ws[4];
    const int t = threadIdx.x;
    float v = partials[t];
    for (int off = 32; off > 0; off >>= 1)
        v += __shfl_down(v, off, 64);
    if ((t & 63) == 0) ws[t >> 6] = v;
    __syncthreads();
    if (t == 0)
        *out = (ws[0] + ws[1] + ws[2] + ws[3]) * (1.0f / (Bb * Nn));
}

extern "C" void kernel_launch(void* const* d_in, const int* in_sizes, int n_in,
                              void* d_out, int out_size, void* d_ws, size_t ws_size,
                              hipStream_t stream) {
    const float* seg_prob  = (const float*)d_in[0];
    const int*   seg_label = (const int*)d_in[1];
    const float* point_rec = (const float*)d_in[2];
    const float* point     = (const float*)d_in[3];
    float*       out       = (float*)d_out;
    float*       partials  = (float*)d_ws;   // 256 floats, rewritten each launch

    criterion_fused_kernel<<<dim3(GRID), dim3(BLOCK), 0, stream>>>(
        seg_prob, seg_label, point_rec, point, partials);
    final_reduce_kernel<<<dim3(1), dim3(256), 0, stream>>>(partials, out);
}